// Round 14
// baseline (95.144 us; speedup 1.0000x reference)
//
#include <hip/hip_runtime.h>
#include <hip/hip_bf16.h>

#define KK 7
#define NL1 8
#define NL2 8
#define IMG 128
#define REG 32            // region edge (pixels) per workgroup
#define RT 38             // o1 tile edge = REG + 6
#define O1P 40            // o1 padded pitch (160B, 16B-aligned; reads <= col 39)
#define XR 44             // xt real rows/cols = REG + 12
#define XTP 44            // xt pitch (176B, 16B-aligned)
#define NBINS 64
#define NHB 16            // histogram blocks per region (4x4 of 8x8)

// Correctness contract (matches XLA-CPU f32 reference, verified round 6):
//  conv1: per-pixel strict sequential FMA chain, taps ordered dp->dq->c(fastest)
//  out1 : materialized as f32 (and zeroed outside the image = conv2 padding)
//  conv2: per-filter strict sequential FMA chain, taps ordered dp->dq
// Restructuring only changes WHERE operands come from, never per-chain order.
//
// Round-14: revert round-13's HST=33 (neutral-negative; conflicts counter is
// not hist-driven and not on the critical path). Back to round-11's proven
// 82us base with ONE change: conv1 tasks widened to 8 output cols
// (19 row-pairs x 5 chunks = 95 tasks). Per e-step 12 b128 reads feed 336
// FMAs (was 9 reads / 168 FMAs) -> half the latency-exposure windows in the
// VALU-stall-bound regime. 8-wide reads at c1=32 touch cols 44..47 which
// wrap into the next row / array tail: those values feed ONLY o1 pad cols
// 38/39 (k=6,7 at dq>=6), which conv2 never reads. LDS OOB reads don't fault.

#define LDX16(dst, plane, row, col)                                          \
    { float4 t_;                                                             \
      t_ = *(const float4*)&xt[plane][row][col];                             \
      dst[0]=t_.x; dst[1]=t_.y; dst[2]=t_.z; dst[3]=t_.w;                    \
      t_ = *(const float4*)&xt[plane][row][(col)+4];                         \
      dst[4]=t_.x; dst[5]=t_.y; dst[6]=t_.z; dst[7]=t_.w;                    \
      t_ = *(const float4*)&xt[plane][row][(col)+8];                         \
      dst[8]=t_.x; dst[9]=t_.y; dst[10]=t_.z; dst[11]=t_.w;                  \
      t_ = *(const float4*)&xt[plane][row][(col)+12];                        \
      dst[12]=t_.x; dst[13]=t_.y; dst[14]=t_.z; dst[15]=t_.w; }

// 8-wide tap burst for one output row at kernel row dp.
// Per accumulator: dq ascending, c fastest (f0 -> f1 -> f2) — contract order.
#define C1TAPS8(p0,p1,p2,p3,p4,p5,p6,p7, dp)                                 \
    _Pragma("unroll")                                                        \
    for (int dq = 0; dq < KK; ++dq) {                                        \
        float wa = w1g[(dp) * 7 + dq];                                       \
        float wb = w1g[49 + (dp) * 7 + dq];                                  \
        float wc = w1g[98 + (dp) * 7 + dq];                                  \
        p0 = __builtin_fmaf(f0[dq + 0], wa, p0);                             \
        p0 = __builtin_fmaf(f1[dq + 0], wb, p0);                             \
        p0 = __builtin_fmaf(f2[dq + 0], wc, p0);                             \
        p1 = __builtin_fmaf(f0[dq + 1], wa, p1);                             \
        p1 = __builtin_fmaf(f1[dq + 1], wb, p1);                             \
        p1 = __builtin_fmaf(f2[dq + 1], wc, p1);                             \
        p2 = __builtin_fmaf(f0[dq + 2], wa, p2);                             \
        p2 = __builtin_fmaf(f1[dq + 2], wb, p2);                             \
        p2 = __builtin_fmaf(f2[dq + 2], wc, p2);                             \
        p3 = __builtin_fmaf(f0[dq + 3], wa, p3);                             \
        p3 = __builtin_fmaf(f1[dq + 3], wb, p3);                             \
        p3 = __builtin_fmaf(f2[dq + 3], wc, p3);                             \
        p4 = __builtin_fmaf(f0[dq + 4], wa, p4);                             \
        p4 = __builtin_fmaf(f1[dq + 4], wb, p4);                             \
        p4 = __builtin_fmaf(f2[dq + 4], wc, p4);                             \
        p5 = __builtin_fmaf(f0[dq + 5], wa, p5);                             \
        p5 = __builtin_fmaf(f1[dq + 5], wb, p5);                             \
        p5 = __builtin_fmaf(f2[dq + 5], wc, p5);                             \
        p6 = __builtin_fmaf(f0[dq + 6], wa, p6);                             \
        p6 = __builtin_fmaf(f1[dq + 6], wb, p6);                             \
        p6 = __builtin_fmaf(f2[dq + 6], wc, p6);                             \
        p7 = __builtin_fmaf(f0[dq + 7], wa, p7);                             \
        p7 = __builtin_fmaf(f1[dq + 7], wb, p7);                             \
        p7 = __builtin_fmaf(f2[dq + 7], wc, p7);                             \
    }

__global__ __launch_bounds__(256, 5) void pcanet_fused(
    const float* __restrict__ x,    // (32,3,128,128)
    const float* __restrict__ w1,   // (8,3,7,7)
    const float* __restrict__ w2,   // (8,1,7,7)
    float* __restrict__ out)        // (32, 8*256*64)
{
    const int tid = threadIdx.x;        // 0..255
    const int reg = blockIdx.x;         // 0..15 : 4x4 regions
    const int ch  = blockIdx.y;         // L1 filter index
    const int n   = blockIdx.z;         // image index
    const int P0  = (reg >> 2) * REG;   // region row origin
    const int Q0  = (reg & 3) * REG;    // region col origin

    __shared__ __align__(16) float xt[3][XR][XTP];   // zero-padded x tile (23.2KB)
    __shared__ __align__(16) float o1[RT][O1P];      // f32 conv1 tile (6.1KB)
    __shared__ unsigned int hist[NHB * 32];          // blk*32 + bin>>1, half=bin&1 (2KB)

    const float* __restrict__ w1g = w1 + ch * 147;   // wave-uniform -> s_load
    const float* __restrict__ w2g = w2;              // wave-uniform -> s_load

    // ---- xt fill: lane = tile col (coalesced), rows wave-strided ----
    {
        const int lane = tid & 63;
        const int wv   = tid >> 6;      // 0..3
        const float* xn = x + (size_t)n * 3 * IMG * IMG;
        const int gs = Q0 - 6 + lane;   // global col for this lane
        const bool cok = (gs >= 0) && (gs < IMG);
        if (lane < XTP) {
            for (int c = 0; c < 3; ++c)
                for (int r = wv; r < XR; r += 4) {
                    int gr = P0 - 6 + r;
                    float v = 0.0f;
                    if (cok && gr >= 0 && gr < IMG)
                        v = xn[((size_t)c * IMG + gr) * IMG + gs];
                    xt[c][r][lane] = v;
                }
        }
    }
    for (int i = tid; i < NHB * 32; i += 256) hist[i] = 0u;
    __syncthreads();

    // ---- conv1: 19 row-pairs x 5 col-chunks(of 8) = 95 tasks, single pass ----
    if (tid < 95) {
        int pr = tid / 5;              // row-pair index 0..18
        int c1 = 8 * (tid % 5);        // o1 col base 0,8,16,24,32
        int r0 = 2 * pr;               // o1 rows r0, r0+1
        float a0=0.f,a1=0.f,a2=0.f,a3=0.f,a4=0.f,a5=0.f,a6=0.f,a7=0.f; // row r0
        float b0=0.f,b1=0.f,b2=0.f,b3=0.f,b4=0.f,b5=0.f,b6=0.f,b7=0.f; // row r0+1
        #pragma unroll
        for (int e = 0; e < 8; ++e) {
            float f0[16], f1[16], f2[16];
            LDX16(f0, 0, r0 + e, c1)
            LDX16(f1, 1, r0 + e, c1)
            LDX16(f2, 2, r0 + e, c1)
            if (e < 7)  { C1TAPS8(a0,a1,a2,a3,a4,a5,a6,a7, e) }      // dp = e
            if (e >= 1) { C1TAPS8(b0,b1,b2,b3,b4,b5,b6,b7, e - 1) }  // dp = e-1
        }
        // mask out-of-image o1 pixels to exact 0 (conv2's zero padding)
        int gs0 = Q0 - 3 + c1;
        bool ck[8];
        #pragma unroll
        for (int k = 0; k < 8; ++k) ck[k] = (gs0 + k >= 0 && gs0 + k < IMG);
        {
            int gr = P0 - 3 + r0;
            bool rok = (gr >= 0 && gr < IMG);
            float4 s0, s1;
            s0.x = (rok && ck[0]) ? a0 : 0.f;  s0.y = (rok && ck[1]) ? a1 : 0.f;
            s0.z = (rok && ck[2]) ? a2 : 0.f;  s0.w = (rok && ck[3]) ? a3 : 0.f;
            s1.x = (rok && ck[4]) ? a4 : 0.f;  s1.y = (rok && ck[5]) ? a5 : 0.f;
            s1.z = (rok && ck[6]) ? a6 : 0.f;  s1.w = (rok && ck[7]) ? a7 : 0.f;
            *(float4*)&o1[r0][c1]     = s0;
            *(float4*)&o1[r0][c1 + 4] = s1;
        }
        {
            int gr = P0 - 3 + r0 + 1;
            bool rok = (gr >= 0 && gr < IMG);
            float4 s0, s1;
            s0.x = (rok && ck[0]) ? b0 : 0.f;  s0.y = (rok && ck[1]) ? b1 : 0.f;
            s0.z = (rok && ck[2]) ? b2 : 0.f;  s0.w = (rok && ck[3]) ? b3 : 0.f;
            s1.x = (rok && ck[4]) ? b4 : 0.f;  s1.y = (rok && ck[5]) ? b5 : 0.f;
            s1.z = (rok && ck[6]) ? b6 : 0.f;  s1.w = (rok && ck[7]) ? b7 : 0.f;
            *(float4*)&o1[r0 + 1][c1]     = s0;
            *(float4*)&o1[r0 + 1][c1 + 4] = s1;
        }
    }
    __syncthreads();

    // ---- conv2: thread owns 4 adjacent pixels (r, c0..c0+3) ----
    {
        const int r  = tid >> 3;          // 0..31 output row in region
        const int c0 = (tid & 7) * 4;     // 0..28 output col base (16B-aligned)
        float acc[NL2][4];
        #pragma unroll
        for (int l = 0; l < NL2; ++l)
            #pragma unroll
            for (int k = 0; k < 4; ++k) acc[l][k] = 0.f;

        for (int dp = 0; dp < KK; ++dp) {
            float f[12];
            { float4 t_;
              t_ = *(const float4*)&o1[r + dp][c0];
              f[0]=t_.x; f[1]=t_.y; f[2]=t_.z; f[3]=t_.w;
              t_ = *(const float4*)&o1[r + dp][c0 + 4];
              f[4]=t_.x; f[5]=t_.y; f[6]=t_.z; f[7]=t_.w;
              t_ = *(const float4*)&o1[r + dp][c0 + 8];
              f[8]=t_.x; f[9]=t_.y; f[10]=t_.z; f[11]=t_.w; }
            #pragma unroll
            for (int l = 0; l < NL2; ++l)
                #pragma unroll
                for (int dq = 0; dq < KK; ++dq) {
                    float w = w2g[l * 49 + dp * 7 + dq];   // uniform scalar
                    acc[l][0] = __builtin_fmaf(f[dq + 0], w, acc[l][0]);
                    acc[l][1] = __builtin_fmaf(f[dq + 1], w, acc[l][1]);
                    acc[l][2] = __builtin_fmaf(f[dq + 2], w, acc[l][2]);
                    acc[l][3] = __builtin_fmaf(f[dq + 3], w, acc[l][3]);
                }
        }
        #pragma unroll
        for (int k = 0; k < 4; ++k) {
            int code = 0;
            #pragma unroll
            for (int l = 0; l < NL2; ++l)
                if (acc[l][k] > 0.0f) code |= (1 << l);
            int bin = code >> 2;                       // 0..63
            int bc = (c0 + k) >> 3, br = r >> 3;
            atomicAdd(&hist[(br * 4 + bc) * 32 + (bin >> 1)],
                      1u << (16 * (bin & 1)));
        }
    }
    __syncthreads();

    // ---- write out 16 blocks x 64 bins (unpack halfwords) ----
    size_t planeBase = ((size_t)(n * NL1 + ch)) * 256 * NBINS;
    for (int i = tid; i < NHB * NBINS; i += 256) {
        int bl = i >> 6, bin = i & 63;
        unsigned int w = hist[bl * 32 + (bin >> 1)];
        unsigned int cnt = (w >> (16 * (bin & 1))) & 0xFFFFu;
        int br = bl >> 2, bc = bl & 3;
        int blkg = ((P0 >> 3) + br) * 16 + ((Q0 >> 3) + bc);
        out[planeBase + (size_t)blkg * NBINS + bin] = (float)cnt;
    }
}

extern "C" void kernel_launch(void* const* d_in, const int* in_sizes, int n_in,
                              void* d_out, int out_size, void* d_ws, size_t ws_size,
                              hipStream_t stream) {
    const float* x  = (const float*)d_in[0];
    const float* w1 = (const float*)d_in[1];
    const float* w2 = (const float*)d_in[2];
    float* out = (float*)d_out;

    dim3 grid(16, NL1, 32);   // (4x4 regions, 8 L1 channels, 32 images)
    dim3 block(256);
    pcanet_fused<<<grid, block, 0, stream>>>(x, w1, w2, out);
}